// Round 8
// baseline (1252.209 us; speedup 1.0000x reference)
//
#include <hip/hip_runtime.h>

// Fused 64-layer GRU (H=64, T=2, B=16384) -- MFMA split-bf16, pipelined.
// Only batch rows 8192..16383 feed the output (verified rounds 1-3,7 absmax 0).
//
// Round-8: occupancy isolation experiment vs round 7 (614 us, Occ 41%).
//  * 1024 blocks x 512 threads, 8 USEFUL rows/block; lanes 8-15 duplicate
//    rows 0-7 (no masks, no divergence; MFMA N-tile stays 16). Per-wave
//    instruction stream ~identical to round 7 -- only parallelism changes.
//  * __launch_bounds__(512, 8): VGPR cap 64 (r7 compiled at 60) -> 8 waves/
//    SIMD, 4 independent blocks/CU (LDS 27 KiB x 4 = 108 KiB), 32 waves/CU.
//  * Same 1-barrier/layer phase: waves 0-3 t1-path (gi1+gh1+gates),
//    waves 4-7 t0-path (gi0(l+1)+gates). Split-bf16 GEMMs, fp32 gates.

typedef __attribute__((ext_vector_type(8))) short short8;
typedef __attribute__((ext_vector_type(4))) short short4v;
typedef __attribute__((ext_vector_type(4))) float f32x4;

#define MFMA16(a, b, c) __builtin_amdgcn_mfma_f32_16x16x32_bf16((a), (b), (c), 0, 0, 0)

namespace {

constexpr int kH    = 64;
constexpr int kL    = 64;
constexpr int kB    = 16384;
constexpr int kRPB  = 8;                  // useful rows per block
constexpr int kNR   = 16;                 // MFMA N-tile rows (8-15 duplicates)
constexpr int kGrid = (kB / 2) / kRPB;    // 1024 blocks
constexpr int kBlk  = 512;                // 8 waves
constexpr int kXP   = 72;                 // X pad (shorts; 144 B row stride)
constexpr int kH0P  = 68;                 // H0f pad (floats; 272 B row stride)

// d_ws layout: shorts region then float region.
constexpr size_t nWi       = (size_t)63 * 192 * 64;   // Wih layers 1..63 (idx l-1)
constexpr size_t nWh       = (size_t)64 * 192 * 64;   // Whh layers 0..63
constexpr size_t oWiHi     = 0;
constexpr size_t oWiLo     = oWiHi + nWi;
constexpr size_t oWhHi     = oWiLo + nWi;
constexpr size_t oWhLo     = oWhHi + nWh;
constexpr size_t oShortEnd = oWhLo + nWh;             // 3,121,152 shorts
constexpr size_t nB1       = (size_t)64 * 192;
constexpr size_t oBi       = 0;                       // floats, after short region
constexpr size_t oBh       = nB1;

__device__ __forceinline__ unsigned short rne_bf16(float f) {
    unsigned u = __float_as_uint(f);
    return (unsigned short)((u + 0x7FFFu + ((u >> 16) & 1u)) >> 16);
}
__device__ __forceinline__ float bf2f(unsigned short s) {
    return __uint_as_float(((unsigned)s) << 16);
}
__device__ __forceinline__ float sigm(float v) {
    float e = __expf(-v);
    return __builtin_amdgcn_rcpf(1.0f + e);
}
__device__ __forceinline__ float tanh_fast(float v) {
    float e = __expf(-2.0f * v);
    return (1.0f - e) * __builtin_amdgcn_rcpf(1.0f + e);
}

} // namespace

// ---------------------------------------------------------------------------
// Prep: fp32 weights -> reordered split-bf16 in ws (4 k per thread); biases
// reordered fp32. n-reorder: n = jq*48 + g*16 + jc <-> orig row = g*64+jq*16+jc.
extern "C" __global__ void gru_prep(const float* __restrict__ Whh0,
                                    const float* __restrict__ bih0,
                                    const float* __restrict__ bhh0,
                                    const float* __restrict__ WihL,
                                    const float* __restrict__ WhhL,
                                    const float* __restrict__ bihL,
                                    const float* __restrict__ bhhL,
                                    short* __restrict__ wsS,
                                    float* __restrict__ wsF)
{
    int idx = (int)blockIdx.x * 256 + (int)threadIdx.x;
    const int nWi4 = 63 * 192 * 16;   // float4 granules
    const int nWh4 = 64 * 192 * 16;
    const int nBT  = 64 * 192;

    if (idx < nWi4) {
        const int li  = idx / (192 * 16);
        const int rem = idx % (192 * 16);
        const int n = rem >> 4, k4 = rem & 15;
        const int jq = n / 48, g = (n % 48) / 16, jc = n % 16;
        const int row = g * 64 + jq * 16 + jc;
        const f32x4 w = *reinterpret_cast<const f32x4*>(
            WihL + (size_t)li * 12288 + row * 64 + k4 * 4);
        short4v hi, lo;
        #pragma unroll
        for (int e = 0; e < 4; ++e) {
            const unsigned short h = rne_bf16(w[e]);
            hi[e] = (short)h;
            lo[e] = (short)rne_bf16(w[e] - bf2f(h));
        }
        const size_t off = (size_t)li * 12288 + n * 64 + k4 * 4;
        *reinterpret_cast<short4v*>(wsS + oWiHi + off) = hi;
        *reinterpret_cast<short4v*>(wsS + oWiLo + off) = lo;
        return;
    }
    idx -= nWi4;
    if (idx < nWh4) {
        const int li  = idx / (192 * 16);
        const int rem = idx % (192 * 16);
        const int n = rem >> 4, k4 = rem & 15;
        const int jq = n / 48, g = (n % 48) / 16, jc = n % 16;
        const int row = g * 64 + jq * 16 + jc;
        const float* src = (li == 0) ? (Whh0 + row * 64 + k4 * 4)
                                     : (WhhL + (size_t)(li - 1) * 12288 + row * 64 + k4 * 4);
        const f32x4 w = *reinterpret_cast<const f32x4*>(src);
        short4v hi, lo;
        #pragma unroll
        for (int e = 0; e < 4; ++e) {
            const unsigned short h = rne_bf16(w[e]);
            hi[e] = (short)h;
            lo[e] = (short)rne_bf16(w[e] - bf2f(h));
        }
        const size_t off = (size_t)li * 12288 + n * 64 + k4 * 4;
        *reinterpret_cast<short4v*>(wsS + oWhHi + off) = hi;
        *reinterpret_cast<short4v*>(wsS + oWhLo + off) = lo;
        return;
    }
    idx -= nWh4;
    if (idx < nBT) {
        const int li = idx / 192, n = idx % 192;
        const int jq = n / 48, g = (n % 48) / 16, jc = n % 16;
        const int row = g * 64 + jq * 16 + jc;
        wsF[oBi + idx] = (li == 0) ? bih0[row] : bihL[(size_t)(li - 1) * 192 + row];
        return;
    }
    idx -= nBT;
    if (idx < nBT) {
        const int li = idx / 192, n = idx % 192;
        const int jq = n / 48, g = (n % 48) / 16, jc = n % 16;
        const int row = g * 64 + jq * 16 + jc;
        wsF[oBh + idx] = (li == 0) ? bhh0[row] : bhhL[(size_t)(li - 1) * 192 + row];
        return;
    }
}

// ---------------------------------------------------------------------------
extern "C" __global__ __launch_bounds__(kBlk, 8)
void gru_mfma(const float* __restrict__ x,
              const float* __restrict__ Wih0,
              const float* __restrict__ Wf,
              const float* __restrict__ bfp,
              const short* __restrict__ wsS,
              const float* __restrict__ wsF,
              float* __restrict__ out)
{
    __shared__ __align__(16) short X0hi[2][kNR][kXP];
    __shared__ __align__(16) short X0lo[2][kNR][kXP];
    __shared__ __align__(16) short X1hi[2][kNR][kXP];
    __shared__ __align__(16) short X1lo[2][kNR][kXP];
    __shared__ __align__(16) float H0f[2][kNR][kH0P];

    const int tid  = (int)threadIdx.x;
    const int lane = tid & 63;
    const int l15  = lane & 15;                                  // N-row (8-15 dup)
    const int l4   = lane >> 4;                                  // 0..3
    const int jw   = __builtin_amdgcn_readfirstlane(tid >> 6);   // wave 0..7
    const int jq   = jw & 3;                                     // col-quarter
    const int wt   = jw >> 2;                                    // 0:t1-path 1:t0-path
    // useful rows are 0..7; lanes 8-15 duplicate rows 0-7 end-to-end
    const int grow = kB / 2 + (int)blockIdx.x * kRPB + (l15 & 7);

    const float xv0 = x[grow * 2 + 0];
    const float xv1 = x[grow * 2 + 1];

    const int col4  = jq * 16 + l4 * 4;                // lane's first col
    const int wbase = (jq * 48 + l15) * 64 + l4 * 8;   // weight frag base (+g*1024+ks*32)
    const int xoff  = l4 * 8;                          // X frag k offset (+ks*32)

    // ---------------- prologue: h0(0) from x(t=0), F = 1 ----------------
    if (wt == 1) {
        const float* biL = wsF + oBi + jq * 48 + l4 * 4;   // layer 0
        const float* bhL = wsF + oBh + jq * 48 + l4 * 4;
        const f32x4 w0 = *reinterpret_cast<const f32x4*>(Wih0 + 0 * 64 + col4);
        const f32x4 w1 = *reinterpret_cast<const f32x4*>(Wih0 + 1 * 64 + col4);
        const f32x4 w2 = *reinterpret_cast<const f32x4*>(Wih0 + 2 * 64 + col4);
        const f32x4 bi0 = *reinterpret_cast<const f32x4*>(biL);
        const f32x4 bi1 = *reinterpret_cast<const f32x4*>(biL + 16);
        const f32x4 bi2 = *reinterpret_cast<const f32x4*>(biL + 32);
        const f32x4 bh0 = *reinterpret_cast<const f32x4*>(bhL);
        const f32x4 bh1 = *reinterpret_cast<const f32x4*>(bhL + 16);
        const f32x4 bh2 = *reinterpret_cast<const f32x4*>(bhL + 32);
        short4v ohi, olo; f32x4 fh;
        #pragma unroll
        for (int r = 0; r < 4; ++r) {
            const float rr = sigm(w0[r] * xv0 + bi0[r] + bh0[r]);
            const float zz = sigm(w1[r] * xv0 + bi1[r] + bh1[r]);
            const float nn = tanh_fast(w2[r] * xv0 + bi2[r] + rr * bh2[r]);
            const float h0 = (1.0f - zz) * nn;
            fh[r] = h0;
            const unsigned short h = rne_bf16(h0);
            ohi[r] = (short)h;
            olo[r] = (short)rne_bf16(h0 - bf2f(h));
        }
        *reinterpret_cast<f32x4*>(&H0f[0][l15][col4])   = fh;
        *reinterpret_cast<short4v*>(&X0hi[0][l15][col4]) = ohi;
        *reinterpret_cast<short4v*>(&X0lo[0][l15][col4]) = olo;
    }
    __syncthreads();

    // ---------------- pipelined layer loop: one barrier per phase ----------
    #pragma unroll 1
    for (int l = 0; l < kL; ++l) {
        const int rb = l & 1, wb = rb ^ 1;

        if (wt == 0) {
            // ======== t1 path: gi1 = Wi(l)*X1(l-1), gh1 = Wh(l)*h0(l) ======
            f32x4 ai[3], ah[3];
            #pragma unroll
            for (int g = 0; g < 3; ++g) {
                ai[g] = f32x4{0.f, 0.f, 0.f, 0.f};
                ah[g] = f32x4{0.f, 0.f, 0.f, 0.f};
            }

            if (l == 0) {
                // F = 1: gi1 directly from x(t=1)
                const f32x4 w0 = *reinterpret_cast<const f32x4*>(Wih0 + 0 * 64 + col4);
                const f32x4 w1 = *reinterpret_cast<const f32x4*>(Wih0 + 1 * 64 + col4);
                const f32x4 w2 = *reinterpret_cast<const f32x4*>(Wih0 + 2 * 64 + col4);
                #pragma unroll
                for (int r = 0; r < 4; ++r) {
                    ai[0][r] = w0[r] * xv1;
                    ai[1][r] = w1[r] * xv1;
                    ai[2][r] = w2[r] * xv1;
                }
            } else {
                short8 xh[2], xl[2];
                #pragma unroll
                for (int ks = 0; ks < 2; ++ks) {
                    xh[ks] = *reinterpret_cast<const short8*>(&X1hi[rb][l15][ks * 32 + xoff]);
                    xl[ks] = *reinterpret_cast<const short8*>(&X1lo[rb][l15][ks * 32 + xoff]);
                }
                const short* WiH = wsS + oWiHi + (size_t)(l - 1) * 12288;
                const short* WiL = wsS + oWiLo + (size_t)(l - 1) * 12288;
                #pragma unroll
                for (int g = 0; g < 3; ++g)
                    #pragma unroll
                    for (int ks = 0; ks < 2; ++ks) {
                        const short8 wh_ = *reinterpret_cast<const short8*>(WiH + wbase + g * 1024 + ks * 32);
                        const short8 wl_ = *reinterpret_cast<const short8*>(WiL + wbase + g * 1024 + ks * 32);
                        ai[g] = MFMA16(wh_, xh[ks], ai[g]);
                        ai[g] = MFMA16(wl_, xh[ks], ai[g]);
                        ai[g] = MFMA16(wh_, xl[ks], ai[g]);
                    }
            }
            {
                short8 hh[2], hl[2];
                #pragma unroll
                for (int ks = 0; ks < 2; ++ks) {
                    hh[ks] = *reinterpret_cast<const short8*>(&X0hi[rb][l15][ks * 32 + xoff]);
                    hl[ks] = *reinterpret_cast<const short8*>(&X0lo[rb][l15][ks * 32 + xoff]);
                }
                const short* WhH = wsS + oWhHi + (size_t)l * 12288;
                const short* WhL = wsS + oWhLo + (size_t)l * 12288;
                #pragma unroll
                for (int g = 0; g < 3; ++g)
                    #pragma unroll
                    for (int ks = 0; ks < 2; ++ks) {
                        const short8 wh_ = *reinterpret_cast<const short8*>(WhH + wbase + g * 1024 + ks * 32);
                        const short8 wl_ = *reinterpret_cast<const short8*>(WhL + wbase + g * 1024 + ks * 32);
                        ah[g] = MFMA16(wh_, hh[ks], ah[g]);
                        ah[g] = MFMA16(wl_, hh[ks], ah[g]);
                        ah[g] = MFMA16(wh_, hl[ks], ah[g]);
                    }
            }
            // t1 gates, fully in-register
            const float* biL = wsF + oBi + (size_t)l * 192 + jq * 48 + l4 * 4;
            const float* bhL = wsF + oBh + (size_t)l * 192 + jq * 48 + l4 * 4;
            const f32x4 bi0 = *reinterpret_cast<const f32x4*>(biL);
            const f32x4 bi1 = *reinterpret_cast<const f32x4*>(biL + 16);
            const f32x4 bi2 = *reinterpret_cast<const f32x4*>(biL + 32);
            const f32x4 bh0 = *reinterpret_cast<const f32x4*>(bhL);
            const f32x4 bh1 = *reinterpret_cast<const f32x4*>(bhL + 16);
            const f32x4 bh2 = *reinterpret_cast<const f32x4*>(bhL + 32);
            const f32x4 h0v = *reinterpret_cast<const f32x4*>(&H0f[rb][l15][col4]);
            short4v ohi, olo;
            #pragma unroll
            for (int r = 0; r < 4; ++r) {
                const float rr = sigm(ai[0][r] + bi0[r] + ah[0][r] + bh0[r]);
                const float zz = sigm(ai[1][r] + bi1[r] + ah[1][r] + bh1[r]);
                const float nn = tanh_fast(ai[2][r] + bi2[r] + rr * (ah[2][r] + bh2[r]));
                const float h1 = (1.0f - zz) * nn + zz * h0v[r];
                const unsigned short h = rne_bf16(h1);
                ohi[r] = (short)h;
                olo[r] = (short)rne_bf16(h1 - bf2f(h));
            }
            *reinterpret_cast<short4v*>(&X1hi[wb][l15][col4]) = ohi;
            *reinterpret_cast<short4v*>(&X1lo[wb][l15][col4]) = olo;
        } else if (l < kL - 1) {
            // ======== t0 path: gi0 = Wi(l+1)*h0(l) -> h0(l+1) =============
            f32x4 a0[3];
            #pragma unroll
            for (int g = 0; g < 3; ++g) a0[g] = f32x4{0.f, 0.f, 0.f, 0.f};
            short8 hh[2], hl[2];
            #pragma unroll
            for (int ks = 0; ks < 2; ++ks) {
                hh[ks] = *reinterpret_cast<const short8*>(&X0hi[rb][l15][ks * 32 + xoff]);
                hl[ks] = *reinterpret_cast<const short8*>(&X0lo[rb][l15][ks * 32 + xoff]);
            }
            const short* WiH = wsS + oWiHi + (size_t)l * 12288;   // layer l+1
            const short* WiL = wsS + oWiLo + (size_t)l * 12288;
            #pragma unroll
            for (int g = 0; g < 3; ++g)
                #pragma unroll
                for (int ks = 0; ks < 2; ++ks) {
                    const short8 wh_ = *reinterpret_cast<const short8*>(WiH + wbase + g * 1024 + ks * 32);
                    const short8 wl_ = *reinterpret_cast<const short8*>(WiL + wbase + g * 1024 + ks * 32);
                    a0[g] = MFMA16(wh_, hh[ks], a0[g]);
                    a0[g] = MFMA16(wl_, hh[ks], a0[g]);
                    a0[g] = MFMA16(wh_, hl[ks], a0[g]);
                }
            const float* biL = wsF + oBi + (size_t)(l + 1) * 192 + jq * 48 + l4 * 4;
            const float* bhL = wsF + oBh + (size_t)(l + 1) * 192 + jq * 48 + l4 * 4;
            const f32x4 bi0 = *reinterpret_cast<const f32x4*>(biL);
            const f32x4 bi1 = *reinterpret_cast<const f32x4*>(biL + 16);
            const f32x4 bi2 = *reinterpret_cast<const f32x4*>(biL + 32);
            const f32x4 bh0 = *reinterpret_cast<const f32x4*>(bhL);
            const f32x4 bh1 = *reinterpret_cast<const f32x4*>(bhL + 16);
            const f32x4 bh2 = *reinterpret_cast<const f32x4*>(bhL + 32);
            short4v ohi, olo; f32x4 fh;
            #pragma unroll
            for (int r = 0; r < 4; ++r) {
                const float rr = sigm(a0[0][r] + bi0[r] + bh0[r]);
                const float zz = sigm(a0[1][r] + bi1[r] + bh1[r]);
                const float nn = tanh_fast(a0[2][r] + bi2[r] + rr * bh2[r]);
                const float h0 = (1.0f - zz) * nn;
                fh[r] = h0;
                const unsigned short h = rne_bf16(h0);
                ohi[r] = (short)h;
                olo[r] = (short)rne_bf16(h0 - bf2f(h));
            }
            *reinterpret_cast<f32x4*>(&H0f[wb][l15][col4])   = fh;
            *reinterpret_cast<short4v*>(&X0hi[wb][l15][col4]) = ohi;
            *reinterpret_cast<short4v*>(&X0lo[wb][l15][col4]) = olo;
        }
        __syncthreads();
    }

    // ---------------- final linear --------------------------------------
    // h0(63) sits in H0f[1] (exact fp32, written by P_62); X1(63) in X1[0].
    // Useful rows 0..7 only (rows 8-15 are duplicates).
    if (tid < 16) {
        const int row = tid & 7, t = tid >> 3;
        float a = 0.0f;
        if (t == 0) {
            #pragma unroll
            for (int c = 0; c < 16; ++c) {
                const f32x4 hv = *reinterpret_cast<const f32x4*>(&H0f[1][row][c * 4]);
                #pragma unroll
                for (int e = 0; e < 4; ++e) a = fmaf(Wf[c * 4 + e], hv[e], a);
            }
        } else {
            #pragma unroll
            for (int c = 0; c < 8; ++c) {
                const short8 hv = *reinterpret_cast<const short8*>(&X1hi[0][row][c * 8]);
                const short8 lv = *reinterpret_cast<const short8*>(&X1lo[0][row][c * 8]);
                #pragma unroll
                for (int e = 0; e < 8; ++e)
                    a = fmaf(Wf[c * 8 + e],
                             bf2f((unsigned short)hv[e]) + bf2f((unsigned short)lv[e]), a);
            }
        }
        out[2 * ((int)blockIdx.x * kRPB + row) + t] = a + bfp[0];
    }
}

// ---------------------------------------------------------------------------
extern "C" void kernel_launch(void* const* d_in, const int* in_sizes, int n_in,
                              void* d_out, int out_size, void* d_ws, size_t ws_size,
                              hipStream_t stream) {
    const float* x    = (const float*)d_in[0];
    const float* Wih0 = (const float*)d_in[1];
    const float* Whh0 = (const float*)d_in[2];
    const float* bih0 = (const float*)d_in[3];
    const float* bhh0 = (const float*)d_in[4];
    const float* WihL = (const float*)d_in[5];
    const float* WhhL = (const float*)d_in[6];
    const float* bihL = (const float*)d_in[7];
    const float* bhhL = (const float*)d_in[8];
    const float* Wf   = (const float*)d_in[9];
    const float* bfp  = (const float*)d_in[10];

    short* wsS = (short*)d_ws;
    float* wsF = (float*)((char*)d_ws + oShortEnd * sizeof(short));

    // prep granules: 193536 (Wi f4) + 196608 (Wh f4) + 2*12288 (biases) = 414720
    gru_prep<<<dim3(414720 / 256), dim3(256), 0, stream>>>(
        Whh0, bih0, bhh0, WihL, WhhL, bihL, bhhL, wsS, wsF);

    gru_mfma<<<dim3(kGrid), dim3(kBlk), 0, stream>>>(
        x, Wih0, Wf, bfp, wsS, wsF, (float*)d_out);
}

// Round 9
// 383.680 us; speedup vs baseline: 3.2637x; 3.2637x over previous
//
#include <hip/hip_runtime.h>

// Fused 64-layer GRU (H=64, T=2, B=16384) -- MFMA split-bf16, latency-optimized.
// Only batch rows 8192..16383 feed the output (verified rounds 1-8, absmax 0).
//
// Round-9: attack weight-load latency (r3 vs r7 evidence).
//  * 256 blocks x 512 threads, 32 rows/block (2 N-tiles per wave -> 2 MFMAs
//    per weight fragment). 8 waves = 4 jq x {t1-path, t0-path}. 1 barrier/layer
//    pipelined phase P_l = { t1 of layer l + t0 of layer l+1 }.
//  * Wh(l) staged in LDS, double-buffered: global_load_lds (16B) issued at top
//    of phase l-1 for layer l -> full phase of latency lead, zero VGPR cost.
//    ws Wh region is PRE-SWIZZLED (short off ^= (n&7)<<3) so the linear LDS
//    copy gives bank-floor ds_read_b128 fragments (8-pass, = b128 BW floor).
//  * Wi register-prefetched one phase ahead (12 x short8, load-after-use).
//  * Split-bf16 GEMMs (hi*hi + lo*hi + hi*lo), gates/biases/z*h0 fp32.
//  * LDS 149 KiB -> 1 block/CU; launch_bounds(512,2) -> no spill (cap 256).

typedef __attribute__((ext_vector_type(8))) short short8;
typedef __attribute__((ext_vector_type(4))) short short4v;
typedef __attribute__((ext_vector_type(4))) float f32x4;

#define MFMA16(a, b, c) __builtin_amdgcn_mfma_f32_16x16x32_bf16((a), (b), (c), 0, 0, 0)

#define GLOAD_LDS16(gsrc, ldst)                                                \
    __builtin_amdgcn_global_load_lds(                                          \
        (const __attribute__((address_space(1))) void*)(gsrc),                 \
        (__attribute__((address_space(3))) void*)(ldst), 16, 0, 0)

namespace {

constexpr int kH    = 64;
constexpr int kL    = 64;
constexpr int kB    = 16384;
constexpr int kRPB  = 32;                 // rows per block
constexpr int kGrid = (kB / 2) / kRPB;    // 256 blocks
constexpr int kBlk  = 512;                // 8 waves
constexpr int kXP   = 72;                 // X pad (shorts; 144 B row stride)
constexpr int kH0P  = 68;                 // H0f pad (floats; 272 B row stride)

// d_ws layout: shorts region then float region. Wh region content swizzled.
constexpr size_t nWi       = (size_t)63 * 192 * 64;   // Wih layers 1..63 (idx l-1)
constexpr size_t nWh       = (size_t)64 * 192 * 64;   // Whh layers 0..63
constexpr size_t oWiHi     = 0;
constexpr size_t oWiLo     = oWiHi + nWi;
constexpr size_t oWhHi     = oWiLo + nWi;
constexpr size_t oWhLo     = oWhHi + nWh;
constexpr size_t oShortEnd = oWhLo + nWh;             // 3,121,152 shorts
constexpr size_t nB1       = (size_t)64 * 192;
constexpr size_t oBi       = 0;                       // floats, after short region
constexpr size_t oBh       = nB1;

__device__ __forceinline__ unsigned short rne_bf16(float f) {
    unsigned u = __float_as_uint(f);
    return (unsigned short)((u + 0x7FFFu + ((u >> 16) & 1u)) >> 16);
}
__device__ __forceinline__ float bf2f(unsigned short s) {
    return __uint_as_float(((unsigned)s) << 16);
}
__device__ __forceinline__ float sigm(float v) {
    float e = __expf(-v);
    return __builtin_amdgcn_rcpf(1.0f + e);
}
__device__ __forceinline__ float tanh_fast(float v) {
    float e = __expf(-2.0f * v);
    return (1.0f - e) * __builtin_amdgcn_rcpf(1.0f + e);
}

} // namespace

// ---------------------------------------------------------------------------
// Prep: fp32 weights -> reordered split-bf16 in ws; biases reordered fp32.
// n-reorder: n = jq*48 + g*16 + jc <-> orig row = g*64+jq*16+jc.
// Wh region additionally bank-swizzled: short off o -> o ^ ((n&7)<<3).
extern "C" __global__ void gru_prep(const float* __restrict__ Whh0,
                                    const float* __restrict__ bih0,
                                    const float* __restrict__ bhh0,
                                    const float* __restrict__ WihL,
                                    const float* __restrict__ WhhL,
                                    const float* __restrict__ bihL,
                                    const float* __restrict__ bhhL,
                                    short* __restrict__ wsS,
                                    float* __restrict__ wsF)
{
    int idx = (int)blockIdx.x * 256 + (int)threadIdx.x;
    const int nWi4 = 63 * 192 * 16;   // float4 granules
    const int nWh4 = 64 * 192 * 16;
    const int nBT  = 64 * 192;

    if (idx < nWi4) {
        const int li  = idx / (192 * 16);
        const int rem = idx % (192 * 16);
        const int n = rem >> 4, k4 = rem & 15;
        const int jq = n / 48, g = (n % 48) / 16, jc = n % 16;
        const int row = g * 64 + jq * 16 + jc;
        const f32x4 w = *reinterpret_cast<const f32x4*>(
            WihL + (size_t)li * 12288 + row * 64 + k4 * 4);
        short4v hi, lo;
        #pragma unroll
        for (int e = 0; e < 4; ++e) {
            const unsigned short h = rne_bf16(w[e]);
            hi[e] = (short)h;
            lo[e] = (short)rne_bf16(w[e] - bf2f(h));
        }
        const size_t off = (size_t)li * 12288 + n * 64 + k4 * 4;  // unswizzled
        *reinterpret_cast<short4v*>(wsS + oWiHi + off) = hi;
        *reinterpret_cast<short4v*>(wsS + oWiLo + off) = lo;
        return;
    }
    idx -= nWi4;
    if (idx < nWh4) {
        const int li  = idx / (192 * 16);
        const int rem = idx % (192 * 16);
        const int n = rem >> 4, k4 = rem & 15;
        const int jq = n / 48, g = (n % 48) / 16, jc = n % 16;
        const int row = g * 64 + jq * 16 + jc;
        const float* src = (li == 0) ? (Whh0 + row * 64 + k4 * 4)
                                     : (WhhL + (size_t)(li - 1) * 12288 + row * 64 + k4 * 4);
        const f32x4 w = *reinterpret_cast<const f32x4*>(src);
        short4v hi, lo;
        #pragma unroll
        for (int e = 0; e < 4; ++e) {
            const unsigned short h = rne_bf16(w[e]);
            hi[e] = (short)h;
            lo[e] = (short)rne_bf16(w[e] - bf2f(h));
        }
        const int o    = (n * 64 + k4 * 4) ^ ((n & 7) << 3);      // bank swizzle
        const size_t off = (size_t)li * 12288 + o;
        *reinterpret_cast<short4v*>(wsS + oWhHi + off) = hi;
        *reinterpret_cast<short4v*>(wsS + oWhLo + off) = lo;
        return;
    }
    idx -= nWh4;
    if (idx < nBT) {
        const int li = idx / 192, n = idx % 192;
        const int jq = n / 48, g = (n % 48) / 16, jc = n % 16;
        const int row = g * 64 + jq * 16 + jc;
        wsF[oBi + idx] = (li == 0) ? bih0[row] : bihL[(size_t)(li - 1) * 192 + row];
        return;
    }
    idx -= nBT;
    if (idx < nBT) {
        const int li = idx / 192, n = idx % 192;
        const int jq = n / 48, g = (n % 48) / 16, jc = n % 16;
        const int row = g * 64 + jq * 16 + jc;
        wsF[oBh + idx] = (li == 0) ? bhh0[row] : bhhL[(size_t)(li - 1) * 192 + row];
        return;
    }
}

// ---------------------------------------------------------------------------
extern "C" __global__ __launch_bounds__(kBlk, 2)
void gru_mfma(const float* __restrict__ x,
              const float* __restrict__ Wih0,
              const float* __restrict__ Wf,
              const float* __restrict__ bfp,
              const short* __restrict__ wsS,
              const float* __restrict__ wsF,
              float* __restrict__ out)
{
    __shared__ __align__(16) short WhL[2][24576];            // 96 KiB (hi|lo)
    __shared__ __align__(16) short X0hi[2][kRPB][kXP];       // 9 KiB each
    __shared__ __align__(16) short X0lo[2][kRPB][kXP];
    __shared__ __align__(16) short X1hi[2][kRPB][kXP];
    __shared__ __align__(16) short X1lo[2][kRPB][kXP];
    __shared__ __align__(16) float H0f[2][kRPB][kH0P];       // 17 KiB

    const int tid  = (int)threadIdx.x;
    const int lane = tid & 63;
    const int l15  = lane & 15;
    const int l4   = lane >> 4;
    const int jw   = __builtin_amdgcn_readfirstlane(tid >> 6);
    const int jq   = jw & 3;
    const int wt   = jw >> 2;                                 // 0:t1 1:t0
    const int rowbase = kB / 2 + (int)blockIdx.x * kRPB;

    const int col4  = jq * 16 + l4 * 4;
    const int wbase = (jq * 48 + l15) * 64 + l4 * 8;          // Wi frag base
    const int xoff  = l4 * 8;
    // Wh LDS frag bases (swizzled, shorts); + g*1024, +12288 for lo
    const int whb0 = ((jq * 48 + l15) * 64 + 0 * 32 + l4 * 8) ^ ((l15 & 7) << 3);
    const int whb1 = ((jq * 48 + l15) * 64 + 1 * 32 + l4 * 8) ^ ((l15 & 7) << 3);

    // stage 48 KiB of layer-L Wh (hi then lo, pre-swizzled content) -> WhL[pbuf]
    auto stage_wh = [&](int L, int pbuf) {
        const int cid0 = jw * 6;
        #pragma unroll
        for (int c = 0; c < 6; ++c) {
            const int cid = cid0 + c;   // 0..23 hi, 24..47 lo (wave-uniform side)
            const short* src = wsS + (cid < 24
                ? oWhHi + (size_t)L * 12288 + cid * 512
                : oWhLo + (size_t)L * 12288 + (cid - 24) * 512) + lane * 8;
            GLOAD_LDS16(src, &WhL[pbuf][cid * 512]);
        }
    };

    short8 wiH[3][2], wiL[3][2];              // prefetched Wi frags (48 VGPR)
    auto load_wi = [&](int idx) {
        const short* WH = wsS + oWiHi + (size_t)idx * 12288 + wbase;
        const short* WL = wsS + oWiLo + (size_t)idx * 12288 + wbase;
        #pragma unroll
        for (int g = 0; g < 3; ++g)
            #pragma unroll
            for (int ks = 0; ks < 2; ++ks) {
                wiH[g][ks] = *reinterpret_cast<const short8*>(WH + g * 1024 + ks * 32);
                wiL[g][ks] = *reinterpret_cast<const short8*>(WL + g * 1024 + ks * 32);
            }
    };

    // ---------------- prologue ----------------
    stage_wh(0, 0);                            // Wh(0) -> buf 0
    load_wi(0);                                // Wi(1) frags (ws idx 0)
    float2 xva = reinterpret_cast<const float2*>(x)[rowbase + 0 * 16 + l15];
    float2 xvb = reinterpret_cast<const float2*>(x)[rowbase + 1 * 16 + l15];

    if (wt == 1) {
        // h0(0) from x(t=0), F = 1: layer-0 gates (h_prev = 0)
        const float* biL = wsF + oBi + jq * 48 + l4 * 4;
        const float* bhL = wsF + oBh + jq * 48 + l4 * 4;
        const f32x4 w0 = *reinterpret_cast<const f32x4*>(Wih0 + 0 * 64 + col4);
        const f32x4 w1 = *reinterpret_cast<const f32x4*>(Wih0 + 1 * 64 + col4);
        const f32x4 w2 = *reinterpret_cast<const f32x4*>(Wih0 + 2 * 64 + col4);
        const f32x4 bi0 = *reinterpret_cast<const f32x4*>(biL);
        const f32x4 bi1 = *reinterpret_cast<const f32x4*>(biL + 16);
        const f32x4 bi2 = *reinterpret_cast<const f32x4*>(biL + 32);
        const f32x4 bh0 = *reinterpret_cast<const f32x4*>(bhL);
        const f32x4 bh1 = *reinterpret_cast<const f32x4*>(bhL + 16);
        const f32x4 bh2 = *reinterpret_cast<const f32x4*>(bhL + 32);
        #pragma unroll
        for (int nt = 0; nt < 2; ++nt) {
            const float xv0 = nt ? xvb.x : xva.x;
            short4v ohi, olo; f32x4 fh;
            #pragma unroll
            for (int r = 0; r < 4; ++r) {
                const float rr = sigm(w0[r] * xv0 + bi0[r] + bh0[r]);
                const float zz = sigm(w1[r] * xv0 + bi1[r] + bh1[r]);
                const float nn = tanh_fast(w2[r] * xv0 + bi2[r] + rr * bh2[r]);
                const float h0 = (1.0f - zz) * nn;
                fh[r] = h0;
                const unsigned short h = rne_bf16(h0);
                ohi[r] = (short)h;
                olo[r] = (short)rne_bf16(h0 - bf2f(h));
            }
            *reinterpret_cast<f32x4*>(&H0f[0][nt * 16 + l15][col4])    = fh;
            *reinterpret_cast<short4v*>(&X0hi[0][nt * 16 + l15][col4]) = ohi;
            *reinterpret_cast<short4v*>(&X0lo[0][nt * 16 + l15][col4]) = olo;
        }
    }
    __syncthreads();

    // ---------------- layer loop: one barrier per phase ----------------
    #pragma unroll 1
    for (int l = 0; l < kL; ++l) {
        const int rb = l & 1, wb = rb ^ 1;     // pb_read = rb; staging -> wb

        if (l < kL - 1) stage_wh(l + 1, wb);   // Wh(l+1) -> other buffer

        if (wt == 0) {
            // ======== t1 path: gi1 = Wi(l)*X1(l-1), gh1 = Wh(l)*h0(l) ======
            f32x4 ai[3][2], ah[3][2];
            #pragma unroll
            for (int g = 0; g < 3; ++g)
                #pragma unroll
                for (int nt = 0; nt < 2; ++nt) {
                    ai[g][nt] = f32x4{0.f, 0.f, 0.f, 0.f};
                    ah[g][nt] = f32x4{0.f, 0.f, 0.f, 0.f};
                }

            if (l == 0) {
                const f32x4 w0 = *reinterpret_cast<const f32x4*>(Wih0 + 0 * 64 + col4);
                const f32x4 w1 = *reinterpret_cast<const f32x4*>(Wih0 + 1 * 64 + col4);
                const f32x4 w2 = *reinterpret_cast<const f32x4*>(Wih0 + 2 * 64 + col4);
                #pragma unroll
                for (int nt = 0; nt < 2; ++nt) {
                    const float xv1 = nt ? xvb.y : xva.y;
                    #pragma unroll
                    for (int r = 0; r < 4; ++r) {
                        ai[0][nt][r] = w0[r] * xv1;
                        ai[1][nt][r] = w1[r] * xv1;
                        ai[2][nt][r] = w2[r] * xv1;
                    }
                }
            } else {
                short8 xh[2][2], xl[2][2];     // [nt][ks]
                #pragma unroll
                for (int nt = 0; nt < 2; ++nt)
                    #pragma unroll
                    for (int ks = 0; ks < 2; ++ks) {
                        xh[nt][ks] = *reinterpret_cast<const short8*>(
                            &X1hi[rb][nt * 16 + l15][ks * 32 + xoff]);
                        xl[nt][ks] = *reinterpret_cast<const short8*>(
                            &X1lo[rb][nt * 16 + l15][ks * 32 + xoff]);
                    }
                #pragma unroll
                for (int g = 0; g < 3; ++g)
                    #pragma unroll
                    for (int ks = 0; ks < 2; ++ks)
                        #pragma unroll
                        for (int nt = 0; nt < 2; ++nt) {
                            ai[g][nt] = MFMA16(wiH[g][ks], xh[nt][ks], ai[g][nt]);
                            ai[g][nt] = MFMA16(wiL[g][ks], xh[nt][ks], ai[g][nt]);
                            ai[g][nt] = MFMA16(wiH[g][ks], xl[nt][ks], ai[g][nt]);
                        }
            }
            // prefetch next phase's Wi (ws idx l) after consumption
            if (l >= 1 && l <= kL - 2) load_wi(l);

            // gh1 from LDS-staged Wh(l)
            {
                short8 hh[2][2], hl[2][2];
                #pragma unroll
                for (int nt = 0; nt < 2; ++nt)
                    #pragma unroll
                    for (int ks = 0; ks < 2; ++ks) {
                        hh[nt][ks] = *reinterpret_cast<const short8*>(
                            &X0hi[rb][nt * 16 + l15][ks * 32 + xoff]);
                        hl[nt][ks] = *reinterpret_cast<const short8*>(
                            &X0lo[rb][nt * 16 + l15][ks * 32 + xoff]);
                    }
                #pragma unroll
                for (int g = 0; g < 3; ++g)
                    #pragma unroll
                    for (int ks = 0; ks < 2; ++ks) {
                        const int wo = (ks ? whb1 : whb0) + g * 1024;
                        const short8 whh = *reinterpret_cast<const short8*>(
                            &WhL[rb][wo]);
                        const short8 whl = *reinterpret_cast<const short8*>(
                            &WhL[rb][12288 + wo]);
                        #pragma unroll
                        for (int nt = 0; nt < 2; ++nt) {
                            ah[g][nt] = MFMA16(whh, hh[nt][ks], ah[g][nt]);
                            ah[g][nt] = MFMA16(whl, hh[nt][ks], ah[g][nt]);
                            ah[g][nt] = MFMA16(whh, hl[nt][ks], ah[g][nt]);
                        }
                    }
            }
            // t1 gates
            const float* biL = wsF + oBi + (size_t)l * 192 + jq * 48 + l4 * 4;
            const float* bhL = wsF + oBh + (size_t)l * 192 + jq * 48 + l4 * 4;
            const f32x4 bi0 = *reinterpret_cast<const f32x4*>(biL);
            const f32x4 bi1 = *reinterpret_cast<const f32x4*>(biL + 16);
            const f32x4 bi2 = *reinterpret_cast<const f32x4*>(biL + 32);
            const f32x4 bh0 = *reinterpret_cast<const f32x4*>(bhL);
            const f32x4 bh1 = *reinterpret_cast<const f32x4*>(bhL + 16);
            const f32x4 bh2 = *reinterpret_cast<const f32x4*>(bhL + 32);
            #pragma unroll
            for (int nt = 0; nt < 2; ++nt) {
                const f32x4 h0v = *reinterpret_cast<const f32x4*>(
                    &H0f[rb][nt * 16 + l15][col4]);
                short4v ohi, olo;
                #pragma unroll
                for (int r = 0; r < 4; ++r) {
                    const float rr = sigm(ai[0][nt][r] + bi0[r] + ah[0][nt][r] + bh0[r]);
                    const float zz = sigm(ai[1][nt][r] + bi1[r] + ah[1][nt][r] + bh1[r]);
                    const float nn = tanh_fast(ai[2][nt][r] + bi2[r] +
                                               rr * (ah[2][nt][r] + bh2[r]));
                    const float h1 = (1.0f - zz) * nn + zz * h0v[r];
                    const unsigned short h = rne_bf16(h1);
                    ohi[r] = (short)h;
                    olo[r] = (short)rne_bf16(h1 - bf2f(h));
                }
                *reinterpret_cast<short4v*>(&X1hi[wb][nt * 16 + l15][col4]) = ohi;
                *reinterpret_cast<short4v*>(&X1lo[wb][nt * 16 + l15][col4]) = olo;
            }
        } else if (l < kL - 1) {
            // ======== t0 path: gi0 = Wi(l+1)*h0(l) -> h0(l+1) =============
            f32x4 a0[3][2];
            #pragma unroll
            for (int g = 0; g < 3; ++g)
                #pragma unroll
                for (int nt = 0; nt < 2; ++nt)
                    a0[g][nt] = f32x4{0.f, 0.f, 0.f, 0.f};
            short8 hh[2][2], hl[2][2];
            #pragma unroll
            for (int nt = 0; nt < 2; ++nt)
                #pragma unroll
                for (int ks = 0; ks < 2; ++ks) {
                    hh[nt][ks] = *reinterpret_cast<const short8*>(
                        &X0hi[rb][nt * 16 + l15][ks * 32 + xoff]);
                    hl[nt][ks] = *reinterpret_cast<const short8*>(
                        &X0lo[rb][nt * 16 + l15][ks * 32 + xoff]);
                }
            #pragma unroll
            for (int g = 0; g < 3; ++g)
                #pragma unroll
                for (int ks = 0; ks < 2; ++ks)
                    #pragma unroll
                    for (int nt = 0; nt < 2; ++nt) {
                        a0[g][nt] = MFMA16(wiH[g][ks], hh[nt][ks], a0[g][nt]);
                        a0[g][nt] = MFMA16(wiL[g][ks], hh[nt][ks], a0[g][nt]);
                        a0[g][nt] = MFMA16(wiH[g][ks], hl[nt][ks], a0[g][nt]);
                    }
            // prefetch Wi for next phase (ws idx l+1) after consumption
            if (l + 1 <= kL - 2) load_wi(l + 1);

            const float* biL = wsF + oBi + (size_t)(l + 1) * 192 + jq * 48 + l4 * 4;
            const float* bhL = wsF + oBh + (size_t)(l + 1) * 192 + jq * 48 + l4 * 4;
            const f32x4 bi0 = *reinterpret_cast<const f32x4*>(biL);
            const f32x4 bi1 = *reinterpret_cast<const f32x4*>(biL + 16);
            const f32x4 bi2 = *reinterpret_cast<const f32x4*>(biL + 32);
            const f32x4 bh0 = *reinterpret_cast<const f32x4*>(bhL);
            const f32x4 bh1 = *reinterpret_cast<const f32x4*>(bhL + 16);
            const f32x4 bh2 = *reinterpret_cast<const f32x4*>(bhL + 32);
            #pragma unroll
            for (int nt = 0; nt < 2; ++nt) {
                short4v ohi, olo; f32x4 fh;
                #pragma unroll
                for (int r = 0; r < 4; ++r) {
                    const float rr = sigm(a0[0][nt][r] + bi0[r] + bh0[r]);
                    const float zz = sigm(a0[1][nt][r] + bi1[r] + bh1[r]);
                    const float nn = tanh_fast(a0[2][nt][r] + bi2[r] + rr * bh2[r]);
                    const float h0 = (1.0f - zz) * nn;
                    fh[r] = h0;
                    const unsigned short h = rne_bf16(h0);
                    ohi[r] = (short)h;
                    olo[r] = (short)rne_bf16(h0 - bf2f(h));
                }
                *reinterpret_cast<f32x4*>(&H0f[wb][nt * 16 + l15][col4])    = fh;
                *reinterpret_cast<short4v*>(&X0hi[wb][nt * 16 + l15][col4]) = ohi;
                *reinterpret_cast<short4v*>(&X0lo[wb][nt * 16 + l15][col4]) = olo;
            }
        }
        __syncthreads();
    }

    // ---------------- final linear --------------------------------------
    // h0(63) in H0f[1] (fp32, phase 62); X1(63) in X1[0] (phase 63).
    if (jw == 0) {
        const int row = lane & 31, t = lane >> 5;
        float a = 0.0f;
        if (t == 0) {
            #pragma unroll
            for (int c = 0; c < 16; ++c) {
                const f32x4 hv = *reinterpret_cast<const f32x4*>(&H0f[1][row][c * 4]);
                #pragma unroll
                for (int e = 0; e < 4; ++e) a = fmaf(Wf[c * 4 + e], hv[e], a);
            }
        } else {
            #pragma unroll
            for (int c = 0; c < 8; ++c) {
                const short8 hv = *reinterpret_cast<const short8*>(&X1hi[0][row][c * 8]);
                const short8 lv = *reinterpret_cast<const short8*>(&X1lo[0][row][c * 8]);
                #pragma unroll
                for (int e = 0; e < 8; ++e)
                    a = fmaf(Wf[c * 8 + e],
                             bf2f((unsigned short)hv[e]) + bf2f((unsigned short)lv[e]), a);
            }
        }
        out[2 * ((int)blockIdx.x * kRPB + row) + t] = a + bfp[0];
    }
}

// ---------------------------------------------------------------------------
extern "C" void kernel_launch(void* const* d_in, const int* in_sizes, int n_in,
                              void* d_out, int out_size, void* d_ws, size_t ws_size,
                              hipStream_t stream) {
    const float* x    = (const float*)d_in[0];
    const float* Wih0 = (const float*)d_in[1];
    const float* Whh0 = (const float*)d_in[2];
    const float* bih0 = (const float*)d_in[3];
    const float* bhh0 = (const float*)d_in[4];
    const float* WihL = (const float*)d_in[5];
    const float* WhhL = (const float*)d_in[6];
    const float* bihL = (const float*)d_in[7];
    const float* bhhL = (const float*)d_in[8];
    const float* Wf   = (const float*)d_in[9];
    const float* bfp  = (const float*)d_in[10];

    short* wsS = (short*)d_ws;
    float* wsF = (float*)((char*)d_ws + oShortEnd * sizeof(short));

    // prep granules: 193536 (Wi f4) + 196608 (Wh f4) + 2*12288 (biases) = 414720
    gru_prep<<<dim3(414720 / 256), dim3(256), 0, stream>>>(
        Whh0, bih0, bhh0, WihL, WhhL, bihL, bhhL, wsS, wsF);

    gru_mfma<<<dim3(kGrid), dim3(kBlk), 0, stream>>>(
        x, Wih0, Wf, bfp, wsS, wsF, (float*)d_out);
}